// Round 3
// baseline (334.570 us; speedup 1.0000x reference)
//
#include <hip/hip_runtime.h>
#include <hip/hip_bf16.h>
#include <stdint.h>

// Problem constants (B=4, T=2048, D=256, M=128, L=16, P=2048)
// fp16 low-precision path: score sigma ~0.004 -> TAU = 0.05 (~12 sigma)
#define TAU 0.05f

typedef __attribute__((ext_vector_type(8))) _Float16 f16x8;
typedef __attribute__((ext_vector_type(4))) float f32x4;

__device__ __forceinline__ unsigned short f2h(float f) {
  _Float16 h = (_Float16)f;
  return __builtin_bit_cast(unsigned short, h);
}
__device__ __forceinline__ void async_copy16(const void* g, void* l) {
  __builtin_amdgcn_global_load_lds(
      (const __attribute__((address_space(1))) unsigned int*)g,
      (__attribute__((address_space(3))) unsigned int*)l, 16, 0, 0);
}

// ---------------------------------------------------------------------------
// K0: transpose+convert x -> xt[b][d][t] (fp16, K-contig); w1 -> w1t[n][k]
//     (fp16, K-contig); init logits with b2; zero njobs.
// ---------------------------------------------------------------------------
__global__ __launch_bounds__(256) void k_prep(
    const float* __restrict__ x, const float* __restrict__ w1,
    const float* __restrict__ b2,
    unsigned short* __restrict__ xt, unsigned short* __restrict__ w1t,
    float* __restrict__ logits, int* __restrict__ njobs) {
  __shared__ float tileS[64][65];
  int bx = blockIdx.x, tid = threadIdx.x;
  if (bx == 0 && tid == 0) *njobs = 0;
  if (bx < 64) {  // logits init: 16384 floats
    int i = bx * 256 + tid;
    logits[i] = b2[i & 1];
  }
  int j = tid & 63, i0 = tid >> 6;
  if (bx < 512) {                       // x tiles: b(4) * t-tiles(32) * d-tiles(4)
    int b = bx >> 7, t6 = (bx >> 2) & 31, d6 = bx & 3;
    const float* src = x + ((size_t)b * 2048 + (size_t)t6 * 64) * 256 + d6 * 64;
    for (int i = i0; i < 64; i += 4) tileS[i][j] = src[(size_t)i * 256 + j];
    __syncthreads();
    unsigned short* dst = xt + ((size_t)b * 256 + (size_t)d6 * 64) * 2048 + t6 * 64;
    for (int r = i0; r < 64; r += 4) dst[(size_t)r * 2048 + j] = f2h(tileS[j][r]);
  } else {                              // w1 tiles: k-tiles(12) * n-tiles(4)
    int wt = bx - 512;
    int k6 = wt >> 2, n6 = wt & 3;
    const float* src = w1 + ((size_t)k6 * 64) * 256 + n6 * 64;
    for (int i = i0; i < 64; i += 4) tileS[i][j] = src[(size_t)i * 256 + j];
    __syncthreads();
    unsigned short* dst = w1t + ((size_t)n6 * 64) * 768 + k6 * 64;
    for (int r = i0; r < 64; r += 4) dst[(size_t)r * 768 + j] = f2h(tileS[j][r]);
  }
}

// ---------------------------------------------------------------------------
// K1: head_rep/tail_rep = [head;tail] @ x   (fp16 MFMA, fp32 out)
// 64x64 tiles, BK=64, dbuf. Chunk layout: idx = k8*64 + row (K-major grid)
// -> quarter-waves read 16 consecutive 16B chunks (2-way = free).
// A: wave-private staging (no barrier needed for A); fp32->fp16 in regs,
// 2-deep global prefetch. B: wave-shared async (k8 rows 2w,2w+1).
// Barrier at iteration BOTTOM; asyncs issued at top -> full compute phase
// between async issue and the barrier's vmcnt drain.
// ---------------------------------------------------------------------------
__global__ __launch_bounds__(256, 4) void k_gemm_rep(
    const float* __restrict__ head, const float* __restrict__ tail,
    const unsigned short* __restrict__ xt,
    float* __restrict__ hrep, float* __restrict__ trep) {
  __shared__ unsigned short As[2][4096];  // 512 chunks: k8*64 + row
  __shared__ unsigned short Bs[2][4096];  // 512 chunks: k8*64 + col
  int bx = blockIdx.x;
  int ntile = bx >> 8;              // 0..3
  int g = bx & 255;
  int b = g >> 6, mtile = g & 63;   // mtile<32: head, else tail
  const float* Asrc = ((mtile < 32) ? head : tail) +
                      ((size_t)(b * 2048 + (mtile & 31) * 64)) * 2048;
  float* Crep = (mtile < 32) ? hrep : trep;
  const unsigned short* Bsrc = xt + ((size_t)(b * 256 + ntile * 64)) * 2048;

  int tid = threadIdx.x, lane = tid & 63, w = tid >> 6;
  int l15 = lane & 15, l4 = lane >> 4;

  // A: wave w owns rows w*16..w*16+15. Lane: row w*16+l15, k-segment l4*16.
  const float* aptr = Asrc + (size_t)(w * 16 + l15) * 2048 + l4 * 16;
  int aw_chunk0 = (l4 * 2) * 64 + w * 16 + l15;        // k8 = l4*2
  int aw_chunk1 = (l4 * 2 + 1) * 64 + w * 16 + l15;    // k8 = l4*2+1

  // B async: wave w stages k8 = 2w, 2w+1; lane -> col = lane.
  const unsigned short* bg0 = Bsrc + (size_t)lane * 2048 + 2 * w * 8;
  const unsigned short* bg1 = bg0 + 8;

  // fragment chunk offsets (ushort index = chunk*8)
  int ac0 = ((0 + l4) * 64 + w * 16 + l15) * 8;
  int ac1 = ((4 + l4) * 64 + w * 16 + l15) * 8;
  int bc[2][4];
#pragma unroll
  for (int kh = 0; kh < 2; ++kh)
#pragma unroll
    for (int ct = 0; ct < 4; ++ct)
      bc[kh][ct] = ((kh * 4 + l4) * 64 + ct * 16 + l15) * 8;

  f32x4 acc[4];
#pragma unroll
  for (int ct = 0; ct < 4; ++ct) acc[ct] = (f32x4){0.f, 0.f, 0.f, 0.f};

  auto pack_write = [&](float4* av, unsigned short* Abuf) {
    f16x8 p0, p1;
    p0[0] = (_Float16)av[0].x; p0[1] = (_Float16)av[0].y;
    p0[2] = (_Float16)av[0].z; p0[3] = (_Float16)av[0].w;
    p0[4] = (_Float16)av[1].x; p0[5] = (_Float16)av[1].y;
    p0[6] = (_Float16)av[1].z; p0[7] = (_Float16)av[1].w;
    p1[0] = (_Float16)av[2].x; p1[1] = (_Float16)av[2].y;
    p1[2] = (_Float16)av[2].z; p1[3] = (_Float16)av[2].w;
    p1[4] = (_Float16)av[3].x; p1[5] = (_Float16)av[3].y;
    p1[6] = (_Float16)av[3].z; p1[7] = (_Float16)av[3].w;
    *(f16x8*)&Abuf[aw_chunk0 * 8] = p0;
    *(f16x8*)&Abuf[aw_chunk1 * 8] = p1;
  };

  float4 avW[4], avF[4];
  // prologue: stage it=0 into buf0, prefetch it=1 regs, async B(it=0)->buf0
  {
    const float4* ap = (const float4*)aptr;
    avW[0] = ap[0]; avW[1] = ap[1]; avW[2] = ap[2]; avW[3] = ap[3];
  }
  async_copy16(bg0, &Bs[0][(2 * w * 64) * 8]);
  async_copy16(bg1, &Bs[0][((2 * w + 1) * 64) * 8]);
  pack_write(avW, As[0]);
  {
    const float4* ap = (const float4*)(aptr + 64);
    avW[0] = ap[0]; avW[1] = ap[1]; avW[2] = ap[2]; avW[3] = ap[3];
  }
  __syncthreads();

  for (int it = 0; it < 32; ++it) {
    int cur = it & 1, nxt = cur ^ 1;
    // top: issue next-buffer asyncs (drained only at bottom barrier)
    if (it < 31) {
      const unsigned short* g0 = Bsrc + (size_t)lane * 2048 + (it + 1) * 64 + 2 * w * 8;
      async_copy16(g0, &Bs[nxt][(2 * w * 64) * 8]);
      async_copy16(g0 + 8, &Bs[nxt][((2 * w + 1) * 64) * 8]);
    }
    // 2-deep A global prefetch (HBM latency covered by this iter's compute)
    if (it < 30) {
      const float4* ap = (const float4*)(aptr + (it + 2) * 64);
      avF[0] = ap[0]; avF[1] = ap[1]; avF[2] = ap[2]; avF[3] = ap[3];
    }
    const unsigned short* A_ = As[cur];
    const unsigned short* B_ = Bs[cur];
    f16x8 a0 = *(const f16x8*)&A_[ac0];
    f16x8 a1 = *(const f16x8*)&A_[ac1];
#pragma unroll
    for (int ct = 0; ct < 4; ++ct) {
      f16x8 b0 = *(const f16x8*)&B_[bc[0][ct]];
      acc[ct] = __builtin_amdgcn_mfma_f32_16x16x32_f16(a0, b0, acc[ct], 0, 0, 0);
    }
#pragma unroll
    for (int ct = 0; ct < 4; ++ct) {
      f16x8 b1 = *(const f16x8*)&B_[bc[1][ct]];
      acc[ct] = __builtin_amdgcn_mfma_f32_16x16x32_f16(a1, b1, acc[ct], 0, 0, 0);
    }
    // late: convert+write A for it+1 (wave-private, no barrier dependency)
    if (it < 31) {
      pack_write(avW, As[nxt]);
      avW[0] = avF[0]; avW[1] = avF[1]; avW[2] = avF[2]; avW[3] = avF[3];
    }
    __syncthreads();
  }

  // epilogue: C row (in tile) = w*16 + l4*4 + i, col = ntile*64 + ct*16 + l15
  size_t prow = (size_t)b * 2048 + (size_t)(mtile & 31) * 64 + w * 16 + l4 * 4;
  int cb = ntile * 64 + l15;
#pragma unroll
  for (int ct = 0; ct < 4; ++ct)
#pragma unroll
    for (int i = 0; i < 4; ++i)
      Crep[(prow + i) * 256 + cb + ct * 16] = acc[ct][i];
}

// ---------------------------------------------------------------------------
// K2pre: featf16[p][0:256]=h, [256:512]=t, [512:768]=h*t  (fp16)
// ---------------------------------------------------------------------------
__global__ __launch_bounds__(256) void k_feat(
    const float* __restrict__ hrep, const float* __restrict__ trep,
    unsigned short* __restrict__ featf) {
  int gid = blockIdx.x * 256 + threadIdx.x;
  int p = gid >> 6, d0 = (gid & 63) * 4;
  float4 h4 = *(const float4*)&hrep[(size_t)p * 256 + d0];
  float4 t4 = *(const float4*)&trep[(size_t)p * 256 + d0];
  ushort4 a, bb, c;
  a.x = f2h(h4.x); a.y = f2h(h4.y); a.z = f2h(h4.z); a.w = f2h(h4.w);
  bb.x = f2h(t4.x); bb.y = f2h(t4.y); bb.z = f2h(t4.z); bb.w = f2h(t4.w);
  c.x = f2h(h4.x * t4.x); c.y = f2h(h4.y * t4.y);
  c.z = f2h(h4.z * t4.z); c.w = f2h(h4.w * t4.w);
  *(ushort4*)&featf[(size_t)p * 768 + d0] = a;
  *(ushort4*)&featf[(size_t)p * 768 + 256 + d0] = bb;
  *(ushort4*)&featf[(size_t)p * 768 + 512 + d0] = c;
}

// ---------------------------------------------------------------------------
// K2: relu(feat @ w1 + b1) @ w2 + b2 -> logits (fused; atomicAdd partials).
// Same chunked layout / barrier-at-bottom structure as K1; both operands
// staged via async. 64x64 tiles, BK=64, 12 iters, grid 512.
// ---------------------------------------------------------------------------
__global__ __launch_bounds__(256, 4) void k_gemm_mlp(
    const unsigned short* __restrict__ featf, const unsigned short* __restrict__ w1t,
    const float* __restrict__ b1, const float* __restrict__ w2,
    float* __restrict__ logits) {
  __shared__ unsigned short As[2][4096], Bs[2][4096];
  int bx = blockIdx.x;
  int ntile = bx >> 7;   // 0..3
  int mtile = bx & 127;  // 0..127
  int tid = threadIdx.x, lane = tid & 63, w = tid >> 6;
  int l15 = lane & 15, l4 = lane >> 4;

  const unsigned short* Ag = featf + (size_t)(mtile * 64 + lane) * 768 + 2 * w * 8;
  const unsigned short* Bg = w1t + (size_t)(ntile * 64 + lane) * 768 + 2 * w * 8;

  int ac0 = ((0 + l4) * 64 + w * 16 + l15) * 8;
  int ac1 = ((4 + l4) * 64 + w * 16 + l15) * 8;
  int bc[2][4];
#pragma unroll
  for (int kh = 0; kh < 2; ++kh)
#pragma unroll
    for (int ct = 0; ct < 4; ++ct)
      bc[kh][ct] = ((kh * 4 + l4) * 64 + ct * 16 + l15) * 8;

  f32x4 acc[4];
#pragma unroll
  for (int ct = 0; ct < 4; ++ct) acc[ct] = (f32x4){0.f, 0.f, 0.f, 0.f};

  async_copy16(Ag, &As[0][(2 * w * 64) * 8]);
  async_copy16(Ag + 8, &As[0][((2 * w + 1) * 64) * 8]);
  async_copy16(Bg, &Bs[0][(2 * w * 64) * 8]);
  async_copy16(Bg + 8, &Bs[0][((2 * w + 1) * 64) * 8]);
  __syncthreads();

  for (int it = 0; it < 12; ++it) {
    int cur = it & 1, nxt = cur ^ 1;
    if (it < 11) {
      const unsigned short* ga = Ag + (it + 1) * 64;
      const unsigned short* gb = Bg + (it + 1) * 64;
      async_copy16(ga, &As[nxt][(2 * w * 64) * 8]);
      async_copy16(ga + 8, &As[nxt][((2 * w + 1) * 64) * 8]);
      async_copy16(gb, &Bs[nxt][(2 * w * 64) * 8]);
      async_copy16(gb + 8, &Bs[nxt][((2 * w + 1) * 64) * 8]);
    }
    const unsigned short* A_ = As[cur];
    const unsigned short* B_ = Bs[cur];
    f16x8 a0 = *(const f16x8*)&A_[ac0];
    f16x8 a1 = *(const f16x8*)&A_[ac1];
#pragma unroll
    for (int ct = 0; ct < 4; ++ct) {
      f16x8 b0 = *(const f16x8*)&B_[bc[0][ct]];
      acc[ct] = __builtin_amdgcn_mfma_f32_16x16x32_f16(a0, b0, acc[ct], 0, 0, 0);
    }
#pragma unroll
    for (int ct = 0; ct < 4; ++ct) {
      f16x8 b1 = *(const f16x8*)&B_[bc[1][ct]];
      acc[ct] = __builtin_amdgcn_mfma_f32_16x16x32_f16(a1, b1, acc[ct], 0, 0, 0);
    }
    __syncthreads();
  }

  // epilogue: relu(+b1), dot with w2 cols, reduce over 16-lane col group
  float bv[4], w20[4], w21[4];
#pragma unroll
  for (int ct = 0; ct < 4; ++ct) {
    int col = ntile * 64 + ct * 16 + l15;
    bv[ct] = b1[col]; w20[ct] = w2[col * 2]; w21[ct] = w2[col * 2 + 1];
  }
#pragma unroll
  for (int i = 0; i < 4; ++i) {
    float s0 = 0.f, s1 = 0.f;
#pragma unroll
    for (int ct = 0; ct < 4; ++ct) {
      float r = fmaxf(acc[ct][i] + bv[ct], 0.f);
      s0 += r * w20[ct]; s1 += r * w21[ct];
    }
#pragma unroll
    for (int off = 1; off < 16; off <<= 1) {
      s0 += __shfl_xor(s0, off); s1 += __shfl_xor(s1, off);
    }
    if (l15 == 0) {
      int row = mtile * 64 + w * 16 + l4 * 4 + i;
      atomicAdd(&logits[row * 2], s0);
      atomicAdd(&logits[row * 2 + 1], s1);
    }
  }
}

// ---------------------------------------------------------------------------
// K3b: per-mention top-1 + uncertainty set; emit refine jobs
// ---------------------------------------------------------------------------
__global__ void k_select(const float* __restrict__ logits, int* __restrict__ idxv,
                         float* __restrict__ mval, int* __restrict__ cmask,
                         int* __restrict__ njobs, int* __restrict__ jobs) {
  int q = blockIdx.x * 256 + threadIdx.x;
  if (q >= 512) return;
  int base = q * 16;
  float s[16];
#pragma unroll
  for (int i = 0; i < 16; ++i) s[i] = logits[(size_t)(base + i) * 2 + 1];
  float best = s[0]; int bi = 0;
#pragma unroll
  for (int i = 1; i < 16; ++i) if (s[i] > best) { best = s[i]; bi = i; }
  int mask = 0, cnt = 0;
#pragma unroll
  for (int i = 0; i < 16; ++i) if (s[i] > best - TAU) { mask |= 1 << i; ++cnt; }
  idxv[q] = bi; mval[q] = best;
  if (cnt > 1) {
    cmask[q] = mask;
    for (int i = 0; i < 16; ++i)
      if ((mask >> i) & 1) { int j = atomicAdd(njobs, 1); jobs[j] = base + i; }
  } else cmask[q] = 0;
}

// ---------------------------------------------------------------------------
// K3c: fp32 exact score recompute for uncertain candidate pairs
// ---------------------------------------------------------------------------
__global__ __launch_bounds__(1024) void k_refine(
    const int* __restrict__ njobs, const int* __restrict__ jobs,
    const float* __restrict__ head, const float* __restrict__ tail,
    const float* __restrict__ x, const float* __restrict__ w1,
    const float* __restrict__ b1, const float* __restrict__ w2,
    const float* __restrict__ b2, float* __restrict__ refined) {
  __shared__ float hrow[2048], trow[2048], feat[768], red[1024], red2[1024];
  int tid = threadIdx.x, seg = tid >> 8, d = tid & 255;
  int nj = *njobs;
  for (int job = blockIdx.x; job < nj; job += gridDim.x) {
    int code = jobs[job];
    int b = code >> 11, p = code & 2047;
    if (tid < 512)
      *(float4*)&hrow[tid * 4] = *(const float4*)&head[((size_t)(b * 2048 + p)) * 2048 + tid * 4];
    else {
      int u = tid - 512;
      *(float4*)&trow[u * 4] = *(const float4*)&tail[((size_t)(b * 2048 + p)) * 2048 + u * 4];
    }
    __syncthreads();
    float hr = 0.f, tr = 0.f;
    const float* xb = x + ((size_t)b * 2048) * 256 + d;
#pragma unroll 8
    for (int t = seg * 512; t < seg * 512 + 512; ++t) {
      float xv = xb[(size_t)t * 256];
      hr += hrow[t] * xv; tr += trow[t] * xv;
    }
    red[tid] = hr; red2[tid] = tr;
    __syncthreads();
    if (seg == 0) {
      float fh = red[d] + red[256 + d] + red[512 + d] + red[768 + d];
      float ft = red2[d] + red2[256 + d] + red2[512 + d] + red2[768 + d];
      feat[d] = fh; feat[256 + d] = ft; feat[512 + d] = fh * ft;
    }
    __syncthreads();
    float hp = 0.f;
    for (int ii = seg * 192; ii < seg * 192 + 192; ++ii) hp += feat[ii] * w1[(size_t)ii * 256 + d];
    red[tid] = hp;
    __syncthreads();
    if (seg == 0) {
      float hj = b1[d] + red[d] + red[256 + d] + red[512 + d] + red[768 + d];
      hj = fmaxf(hj, 0.f);
      red2[d] = hj * w2[d * 2 + 1];
    }
    __syncthreads();
    for (int s = 128; s > 0; s >>= 1) {
      if (tid < s) red2[tid] += red2[tid + s];
      __syncthreads();
    }
    if (tid == 0) refined[code] = red2[0] + b2[1];
    __syncthreads();
  }
}

// ---------------------------------------------------------------------------
// K4a: rep_m[q][d] = tail_rep[q*16+argmax][d] * max_val
// ---------------------------------------------------------------------------
__global__ __launch_bounds__(256) void k_repm(
    const int* __restrict__ idxv, const float* __restrict__ mval,
    const int* __restrict__ cmask, const float* __restrict__ refined,
    const float* __restrict__ trep, float* __restrict__ repm) {
  int q = blockIdx.x, d = threadIdx.x;
  int mask = cmask[q]; int bi; float v;
  if (mask) {
    bi = -1; v = -1e30f;
    for (int i = 0; i < 16; ++i)
      if ((mask >> i) & 1) { float s = refined[q * 16 + i]; if (s > v) { v = s; bi = i; } }
  } else { bi = idxv[q]; v = mval[q]; }
  repm[(size_t)q * 256 + d] = trep[((size_t)q * 16 + bi) * 256 + d] * v;
}

// ---------------------------------------------------------------------------
// K4b: out[b][t][d] = x + sum_m cmp[b][m][t] * rep_m[b][m][d]  (512 blocks)
// ---------------------------------------------------------------------------
__global__ __launch_bounds__(256) void k_merge(
    const float* __restrict__ cmp, const float* __restrict__ repm,
    const float* __restrict__ x, float* __restrict__ out) {
  __shared__ float cl[128 * 16];
  int bx = blockIdx.x, b = bx >> 7, t0 = (bx & 127) * 16;
  int tid = threadIdx.x;
#pragma unroll
  for (int it = 0; it < 2; ++it) {
    int f = it * 256 + tid;
    int row = f >> 2, c4 = (f & 3) * 4;
    *(float4*)&cl[row * 16 + c4] =
        *(const float4*)&cmp[((size_t)(b * 128 + row)) * 2048 + t0 + c4];
  }
  __syncthreads();
  float acc[16];
#pragma unroll
  for (int i = 0; i < 16; ++i) acc[i] = 0.f;
  int d = tid;
  for (int m = 0; m < 128; ++m) {
    float rv = repm[(size_t)(b * 128 + m) * 256 + d];
    const float4* c4p = (const float4*)&cl[m * 16];
#pragma unroll
    for (int jj = 0; jj < 4; ++jj) {
      float4 c = c4p[jj];
      acc[jj * 4] += c.x * rv; acc[jj * 4 + 1] += c.y * rv;
      acc[jj * 4 + 2] += c.z * rv; acc[jj * 4 + 3] += c.w * rv;
    }
  }
  const float* xb = x + ((size_t)(b * 2048 + t0)) * 256 + d;
  float* ob = out + ((size_t)(b * 2048 + t0)) * 256 + d;
#pragma unroll
  for (int tt = 0; tt < 16; ++tt) ob[(size_t)tt * 256] = xb[(size_t)tt * 256] + acc[tt];
}

// ---------------------------------------------------------------------------
// K5: masked KLDiv mean loss (single block)
// ---------------------------------------------------------------------------
__global__ __launch_bounds__(1024) void k_loss(
    const float* __restrict__ logits, const float* __restrict__ lab,
    const unsigned char* __restrict__ mask, float* __restrict__ out_loss) {
  __shared__ float rs[1024], rc[1024];
  int tid = threadIdx.x;
  float sum = 0.f, cnt = 0.f;
  for (int p = tid; p < 8192; p += 1024) {
    float l0 = logits[(size_t)p * 2], l1 = logits[(size_t)p * 2 + 1];
    float a0 = lab[(size_t)p * 2], a1 = lab[(size_t)p * 2 + 1];
    float mx = fmaxf(l0, l1);
    float lse = mx + logf(expf(l0 - mx) + expf(l1 - mx));
    float pw = 0.f;
    if (a0 > 0.f) pw += a0 * logf(fmaxf(a0, 1e-38f));
    if (a1 > 0.f) pw += a1 * logf(fmaxf(a1, 1e-38f));
    pw -= a0 * (l0 - lse) + a1 * (l1 - lse);
    if (mask[p]) { sum += pw; cnt += 1.f; }
  }
  rs[tid] = sum; rc[tid] = cnt;
  __syncthreads();
  for (int s = 512; s > 0; s >>= 1) {
    if (tid < s) { rs[tid] += rs[tid + s]; rc[tid] += rc[tid + s]; }
    __syncthreads();
  }
  if (tid == 0) *out_loss = rs[0] / (rc[0] * 2.0f);
}

// ---------------------------------------------------------------------------
extern "C" void kernel_launch(void* const* d_in, const int* in_sizes, int n_in,
                              void* d_out, int out_size, void* d_ws, size_t ws_size,
                              hipStream_t stream) {
  (void)in_sizes; (void)n_in; (void)out_size; (void)ws_size;
  const float* head = (const float*)d_in[0];
  const float* tail = (const float*)d_in[1];
  // d_in[2] = lens (uniform L=16) -- unused
  const float* x = (const float*)d_in[3];
  const float* cmp = (const float*)d_in[4];
  const float* lab = (const float*)d_in[5];
  const unsigned char* lmask = (const unsigned char*)d_in[6];
  const float* w1 = (const float*)d_in[7];
  const float* b1 = (const float*)d_in[8];
  const float* w2 = (const float*)d_in[9];
  const float* b2 = (const float*)d_in[10];
  float* out = (float*)d_out;

  char* ws = (char*)d_ws;
  size_t off = 0;
  auto alloc = [&](size_t bytes) -> void* {
    void* p = ws + off; off += (bytes + 255) & ~(size_t)255; return p;
  };
  unsigned short* xt = (unsigned short*)alloc(4ull * 256 * 2048 * 2);
  unsigned short* w1t = (unsigned short*)alloc(256ull * 768 * 2);
  float* hrep = (float*)alloc(8192ull * 256 * 4);
  float* trep = (float*)alloc(8192ull * 256 * 4);
  unsigned short* featf = (unsigned short*)alloc(8192ull * 768 * 2);
  float* logits = (float*)alloc(8192ull * 2 * 4);
  float* refined = (float*)alloc(8192ull * 4);
  int* idxv = (int*)alloc(512 * 4);
  float* mvalv = (float*)alloc(512 * 4);
  int* cmaskv = (int*)alloc(512 * 4);
  int* njobs = (int*)alloc(256);
  int* jobs = (int*)alloc(8192 * 4);
  float* repm = (float*)alloc(512ull * 256 * 4);

  k_prep<<<560, 256, 0, stream>>>(x, w1, b2, xt, w1t, logits, njobs);
  k_gemm_rep<<<1024, 256, 0, stream>>>(head, tail, xt, hrep, trep);
  k_feat<<<2048, 256, 0, stream>>>(hrep, trep, featf);
  k_gemm_mlp<<<512, 256, 0, stream>>>(featf, w1t, b1, w2, logits);
  k_select<<<2, 256, 0, stream>>>(logits, idxv, mvalv, cmaskv, njobs, jobs);
  k_refine<<<256, 1024, 0, stream>>>(njobs, jobs, head, tail, x, w1, b1, w2, b2, refined);
  k_repm<<<512, 256, 0, stream>>>(idxv, mvalv, cmaskv, refined, trep, repm);
  k_merge<<<512, 256, 0, stream>>>(cmp, repm, x, out);
  k_loss<<<1, 1024, 0, stream>>>(logits, lab, lmask, out + 4ull * 2048 * 256);
}